// Round 3
// baseline (14436.816 us; speedup 1.0000x reference)
//
#include <hip/hip_runtime.h>

#define B_    128
#define T_    200
#define TE_   256
#define H_    256
#define PRE_  128
#define OUT_  400
#define BT_   (B_*T_)          // 25600

__device__ __forceinline__ float sigm_(float x){ return 1.f/(1.f+__expf(-x)); }
__device__ __forceinline__ float tanh_(float x){
  x = fminf(15.f, fmaxf(-15.f, x));
  float e = __expf(2.f*x);
  return 1.f - 2.f/(e+1.f);
}
__device__ __forceinline__ float b2f_lo(unsigned u){ return __uint_as_float(u << 16); }
__device__ __forceinline__ float b2f_hi(unsigned u){ return __uint_as_float(u & 0xffff0000u); }
__device__ __forceinline__ unsigned short f2b(float f){
  unsigned u = __float_as_uint(f);
  unsigned r = (u + 0x7fff + ((u >> 16) & 1)) >> 16;   // RNE
  return (unsigned short)r;
}

// one k-step: scalar x times packed-4 bf16 weights into 4 accumulators
#define Q4(xv, wv, A0,A1,A2,A3) \
  A0=fmaf(xv,b2f_lo(wv.x),A0); A1=fmaf(xv,b2f_hi(wv.x),A1); \
  A2=fmaf(xv,b2f_lo(wv.y),A2); A3=fmaf(xv,b2f_hi(wv.y),A3);

// ---------------- transpose/cast: dst[k*N+j] = src[j*Ksrc + col0 + k] ----------------
struct TD { const float* src; void* dst; int N; int Ksrc; int col0; int Keff; int bf16; int blk0; };
struct TDs { TD d[14]; };

__global__ __launch_bounds__(256) void transpose_cast(TDs P)
{
  int bid = blockIdx.x, m = 0;
#pragma unroll
  for (int i = 1; i < 14; ++i) if (bid >= P.d[i].blk0) m = i;
  TD t = P.d[m];
  long gid = (long)(bid - t.blk0)*256 + threadIdx.x;
  long nk = (long)t.N * t.Keff;
  if (gid >= nk) return;
  int k = (int)(gid / t.N);
  int j = (int)(gid % t.N);
  float v = t.src[(size_t)j*t.Ksrc + t.col0 + k];
  if (t.bf16) ((unsigned short*)t.dst)[(size_t)k*t.N + j] = f2b(v);
  else        ((float*)t.dst)[(size_t)k*t.N + j] = v;
}

// ---------------- generic tiled GEMM: C = act(A[M,K] @ WT[K,N] + bias) ----------------
// AMODE: 0 = plain fp32 ptr (lda), 1 = teacher-forced prev-frame loader (targets)
// OUTMODE: 0 = fp32 row-major, 1 = fp32 [b][h][te] transposed, 2 = bf16 [b][h][te]
template<int AMODE, bool RELU, int OUTMODE>
__global__ __launch_bounds__(256) void gemm_k(const float* __restrict__ A, int lda,
                                              const float* __restrict__ WT, int N, int K,
                                              const float* __restrict__ bias,
                                              float* __restrict__ C)
{
  const int tid  = threadIdx.x;
  const int row0 = blockIdx.x * 64;
  const int n0   = blockIdx.y * 64;
  __shared__ float As[16][68];
  __shared__ float Bs[16][64];
  const int tx = tid & 15, ty = tid >> 4;
  float acc[4][4];
#pragma unroll
  for (int i = 0; i < 4; ++i)
#pragma unroll
    for (int j = 0; j < 4; ++j) acc[i][j] = 0.f;

  for (int k0 = 0; k0 < K; k0 += 16){
#pragma unroll
    for (int l = 0; l < 4; ++l){
      int idx = tid + l*256;
      int m2 = idx >> 4, kk = idx & 15;
      float v;
      if (AMODE == 1){
        int r = row0 + m2;
        int t = r % T_;
        v = (t == 0) ? 0.f : A[(size_t)(r-1)*OUT_ + k0 + kk];
      } else {
        v = A[(size_t)(row0+m2)*lda + k0 + kk];
      }
      As[kk][m2] = v;
    }
#pragma unroll
    for (int l = 0; l < 4; ++l){
      int idx = tid + l*256;
      int kk = idx >> 6, j = idx & 63;
      int jg = n0 + j;
      Bs[kk][j] = (jg < N) ? WT[(size_t)(k0+kk)*N + jg] : 0.f;
    }
    __syncthreads();
#pragma unroll
    for (int kk = 0; kk < 16; ++kk){
      float4 a4 = *(const float4*)&As[kk][ty*4];
      float4 b4 = *(const float4*)&Bs[kk][tx*4];
      acc[0][0] = fmaf(a4.x, b4.x, acc[0][0]); acc[0][1] = fmaf(a4.x, b4.y, acc[0][1]);
      acc[0][2] = fmaf(a4.x, b4.z, acc[0][2]); acc[0][3] = fmaf(a4.x, b4.w, acc[0][3]);
      acc[1][0] = fmaf(a4.y, b4.x, acc[1][0]); acc[1][1] = fmaf(a4.y, b4.y, acc[1][1]);
      acc[1][2] = fmaf(a4.y, b4.z, acc[1][2]); acc[1][3] = fmaf(a4.y, b4.w, acc[1][3]);
      acc[2][0] = fmaf(a4.z, b4.x, acc[2][0]); acc[2][1] = fmaf(a4.z, b4.y, acc[2][1]);
      acc[2][2] = fmaf(a4.z, b4.z, acc[2][2]); acc[2][3] = fmaf(a4.z, b4.w, acc[2][3]);
      acc[3][0] = fmaf(a4.w, b4.x, acc[3][0]); acc[3][1] = fmaf(a4.w, b4.y, acc[3][1]);
      acc[3][2] = fmaf(a4.w, b4.z, acc[3][2]); acc[3][3] = fmaf(a4.w, b4.w, acc[3][3]);
    }
    __syncthreads();
  }
#pragma unroll
  for (int i = 0; i < 4; ++i){
    int r = row0 + ty*4 + i;
#pragma unroll
    for (int jj = 0; jj < 4; ++jj){
      int c = n0 + tx*4 + jj;
      if (c < N){
        float v = acc[i][jj] + (bias ? bias[c] : 0.f);
        if (RELU) v = fmaxf(v, 0.f);
        if (OUTMODE == 0){
          C[(size_t)r*N + c] = v;
        } else if (OUTMODE == 1){
          int b = r / TE_, te = r % TE_;
          C[((size_t)b*H_ + c)*TE_ + te] = v;
        } else {
          int b = r / TE_, te = r % TE_;
          ((unsigned short*)C)[((size_t)b*H_ + c)*TE_ + te] = f2b(v);
        }
      }
    }
  }
}

// ---------------- in-loop matvec helpers ----------------
// mv768 geometry: 768 threads; kg = tid/192 (4 K-groups of 64), jt = tid%192 (quad of 4 outputs)
// weights [256][768] bf16, uint2 row stride = 192.
__device__ __forceinline__ void mv768_pair(const uint2* __restrict__ wA, const uint2* __restrict__ wB,
                                           const float* __restrict__ xA, const float* __restrict__ xB,
                                           float* __restrict__ outA, float* __restrict__ outB,
                                           int kg, int jt)
{
  const float4* xa4 = (const float4*)xA;
  const float4* xb4 = (const float4*)xB;
  const uint2* pA = wA + (size_t)(kg*64)*192 + jt;
  const uint2* pB = wB + (size_t)(kg*64)*192 + jt;
  float a0=0,a1=0,a2=0,a3=0, c0=0,c1=0,c2=0,c3=0;
#pragma unroll 4
  for (int k4 = 0; k4 < 16; ++k4){
    float4 x1 = xa4[kg*16+k4];
    float4 x2 = xb4[kg*16+k4];
    uint2 wa0=pA[0],wa1=pA[192],wa2=pA[384],wa3=pA[576]; pA += 768;
    uint2 wb0=pB[0],wb1=pB[192],wb2=pB[384],wb3=pB[576]; pB += 768;
    Q4(x1.x, wa0, a0,a1,a2,a3) Q4(x1.y, wa1, a0,a1,a2,a3)
    Q4(x1.z, wa2, a0,a1,a2,a3) Q4(x1.w, wa3, a0,a1,a2,a3)
    Q4(x2.x, wb0, c0,c1,c2,c3) Q4(x2.y, wb1, c0,c1,c2,c3)
    Q4(x2.z, wb2, c0,c1,c2,c3) Q4(x2.w, wb3, c0,c1,c2,c3)
  }
  *(float4*)(outA + jt*4) = make_float4(a0,a1,a2,a3);
  *(float4*)(outB + jt*4) = make_float4(c0,c1,c2,c3);
}

__device__ __forceinline__ void mv768_single(const uint2* __restrict__ w,
                                             const float* __restrict__ x,
                                             float* __restrict__ out, int kg, int jt)
{
  const float4* x4 = (const float4*)x;
  const uint2* p = w + (size_t)(kg*64)*192 + jt;
  float a0=0,a1=0,a2=0,a3=0;
#pragma unroll 4
  for (int k4 = 0; k4 < 16; ++k4){
    float4 x1 = x4[kg*16+k4];
    uint2 w0=p[0],w1=p[192],w2=p[384],w3=p[576]; p += 768;
    Q4(x1.x, w0, a0,a1,a2,a3) Q4(x1.y, w1, a0,a1,a2,a3)
    Q4(x1.z, w2, a0,a1,a2,a3) Q4(x1.w, w3, a0,a1,a2,a3)
  }
  *(float4*)(out + jt*4) = make_float4(a0,a1,a2,a3);
}

// mv256 geometry: 1024 threads; kg = tid>>6 (16 K-groups of 16), jt = tid&63 (quad of 4 outputs)
// weights [256][256] bf16, uint2 row stride = 64.
__device__ __forceinline__ void mv256_pair(const uint2* __restrict__ wA, const uint2* __restrict__ wB,
                                           const float* __restrict__ x,
                                           float* __restrict__ outA, float* __restrict__ outB,
                                           int kg, int jt)
{
  const float4* x4 = (const float4*)x;
  const uint2* pA = wA + (size_t)(kg*16)*64 + jt;
  const uint2* pB = wB + (size_t)(kg*16)*64 + jt;
  float a0=0,a1=0,a2=0,a3=0, c0=0,c1=0,c2=0,c3=0;
#pragma unroll
  for (int k4 = 0; k4 < 4; ++k4){
    float4 x1 = x4[kg*4+k4];
    uint2 wa0=pA[0],wa1=pA[64],wa2=pA[128],wa3=pA[192]; pA += 256;
    uint2 wb0=pB[0],wb1=pB[64],wb2=pB[128],wb3=pB[192]; pB += 256;
    Q4(x1.x, wa0, a0,a1,a2,a3) Q4(x1.y, wa1, a0,a1,a2,a3)
    Q4(x1.z, wa2, a0,a1,a2,a3) Q4(x1.w, wa3, a0,a1,a2,a3)
    Q4(x1.x, wb0, c0,c1,c2,c3) Q4(x1.y, wb1, c0,c1,c2,c3)
    Q4(x1.z, wb2, c0,c1,c2,c3) Q4(x1.w, wb3, c0,c1,c2,c3)
  }
  *(float4*)(outA + jt*4) = make_float4(a0,a1,a2,a3);
  *(float4*)(outB + jt*4) = make_float4(c0,c1,c2,c3);
}

__device__ __forceinline__ void mv256_single(const uint2* __restrict__ w,
                                             const float* __restrict__ x,
                                             float* __restrict__ out, int kg, int jt)
{
  const float4* x4 = (const float4*)x;
  const uint2* p = w + (size_t)(kg*16)*64 + jt;
  float a0=0,a1=0,a2=0,a3=0;
#pragma unroll
  for (int k4 = 0; k4 < 4; ++k4){
    float4 x1 = x4[kg*4+k4];
    uint2 w0=p[0],w1=p[64],w2=p[128],w3=p[192]; p += 256;
    Q4(x1.x, w0, a0,a1,a2,a3) Q4(x1.y, w1, a0,a1,a2,a3)
    Q4(x1.z, w2, a0,a1,a2,a3) Q4(x1.w, w3, a0,a1,a2,a3)
  }
  *(float4*)(out + jt*4) = make_float4(a0,a1,a2,a3);
}

__device__ __forceinline__ float gru_gate(float gi0,float gi1,float gi2,
                                          float gh0,float gh1,float gh2, float hprev){
  float r = sigm_(gi0+gh0);
  float z = sigm_(gi1+gh1);
  float n = tanh_(gi2 + r*gh2);
  return (1.f-z)*n + z*hprev;
}

// ---------------- persistent per-batch decoder (1024 threads) ----------------
struct DP {
  const float *preGI;
  const unsigned short *pm16, *enc16;
  const unsigned short *awihA, *awhh, *wq, *wp, *g1wih, *g1whh, *g2wih, *g2whh;
  const float *abhh, *g1bih, *g1bhh, *g2bih, *g2bhh, *bp, *v_attn;
  float *decbuf, *aln;
};

__global__ __launch_bounds__(1024) void decoder_kernel(DP P)
{
  const int tid = threadIdx.x;
  const int b = blockIdx.x;

  __shared__ __align__(16) float s_part[12288];                       // 48 KB, reused per phase
  __shared__ __align__(16) float s_g1h[768], s_g2h[768];
  __shared__ __align__(16) float s_ah[H_], s_h1[H_], s_h2[H_], s_av[H_], s_dec[H_];
  __shared__ __align__(16) float s_q[H_], s_dq[H_], s_al[TE_], s_v[H_];
  __shared__ __align__(16) float s_preg[768];
  __shared__ float s_red[4];

  // biases in registers
  float r_bh0=0,r_bh1=0,r_bh2=0, r_1bi0=0,r_1bi1=0,r_1bi2=0;
  float r_2bi0=0,r_2bi1=0,r_2bi2=0, r_bp=0, r_g1bh=0, r_g2bh=0;
  if (tid < H_){
    r_bh0=P.abhh[tid];  r_bh1=P.abhh[H_+tid];  r_bh2=P.abhh[2*H_+tid];
    r_1bi0=P.g1bih[tid]; r_1bi1=P.g1bih[H_+tid]; r_1bi2=P.g1bih[2*H_+tid];
    r_2bi0=P.g2bih[tid]; r_2bi1=P.g2bih[H_+tid]; r_2bi2=P.g2bih[2*H_+tid];
    r_bp=P.bp[tid];
    s_v[tid]=P.v_attn[tid];
    s_ah[tid]=0.f; s_h1[tid]=0.f; s_h2[tid]=0.f; s_av[tid]=0.f;
  } else {
    int j = tid - 256;      // 0..767
    r_g1bh = P.g1bhh[j];
    r_g2bh = P.g2bhh[j];
  }
  __syncthreads();

  const float* preg = P.preGI + (size_t)b*T_*768;
  const uint2* pm2  = (const uint2*)(P.pm16  + (size_t)b*H_*TE_);
  const uint2* en2  = (const uint2*)(P.enc16 + (size_t)b*TE_*H_);
  float* aln_b = P.aln + (size_t)b*T_*TE_;
  float* dec_b = P.decbuf + (size_t)b*T_*H_;

  const uint2* awihA2 = (const uint2*)P.awihA;
  const uint2* awhh2  = (const uint2*)P.awhh;
  const uint2* wq2    = (const uint2*)P.wq;
  const uint2* wpA2   = (const uint2*)P.wp;
  const uint2* wpB2   = ((const uint2*)P.wp) + 16384;   // rows 256..511
  const uint2* g1wih2 = (const uint2*)P.g1wih;
  const uint2* g1whh2 = (const uint2*)P.g1whh;
  const uint2* g2wih2 = (const uint2*)P.g2wih;
  const uint2* g2whh2 = (const uint2*)P.g2whh;

  const int kg8 = tid >> 6, jt8 = tid & 63;             // mv256 geometry

  for (int t = 0; t < T_; ++t){
    // ==== P1: four recurrent 768-wide matvecs (prev-step state) ====
    if (tid < 768){
      const int kg = tid / 192, jt = tid - (tid/192)*192;
      mv768_pair(awihA2, awhh2, s_av, s_ah,
                 s_part + (0*4+kg)*768, s_part + (1*4+kg)*768, kg, jt);
      mv768_pair(g1whh2, g2whh2, s_h1, s_h2,
                 s_part + (2*4+kg)*768, s_part + (3*4+kg)*768, kg, jt);
    } else {
      int i = tid - 768;
      s_preg[i]       = preg[(size_t)t*768 + i];
      s_preg[i + 256] = preg[(size_t)t*768 + i + 256];
      s_preg[i + 512] = preg[(size_t)t*768 + i + 512];
    }
    __syncthreads();                                    // B1
    if (tid < H_){
      float gi0 = s_part[tid]     + s_part[768+tid]     + s_part[1536+tid]     + s_part[2304+tid]     + s_preg[tid];
      float gi1 = s_part[256+tid] + s_part[1024+tid]    + s_part[1792+tid]     + s_part[2560+tid]     + s_preg[256+tid];
      float gi2 = s_part[512+tid] + s_part[1280+tid]    + s_part[2048+tid]     + s_part[2816+tid]     + s_preg[512+tid];
      float gh0 = s_part[3072+tid]     + s_part[3840+tid]     + s_part[4608+tid]     + s_part[5376+tid]     + r_bh0;
      float gh1 = s_part[3072+256+tid] + s_part[3840+256+tid] + s_part[4608+256+tid] + s_part[5376+256+tid] + r_bh1;
      float gh2 = s_part[3072+512+tid] + s_part[3840+512+tid] + s_part[4608+512+tid] + s_part[5376+512+tid] + r_bh2;
      s_ah[tid] = gru_gate(gi0,gi1,gi2, gh0,gh1,gh2, s_ah[tid]);
    } else {
      int j = tid - 256;  // 0..767
      s_g1h[j] = s_part[6144+j] + s_part[6912+j] + s_part[7680+j] + s_part[8448+j] + r_g1bh;
      s_g2h[j] = s_part[9216+j] + s_part[9984+j] + s_part[10752+j] + s_part[11520+j] + r_g2bh;
    }
    __syncthreads();                                    // B2

    // ==== P2: wq@ah and wpA@ah (one phase) ====
    mv256_pair(wq2, wpA2, s_ah, s_part + kg8*256, s_part + 4096 + kg8*256, kg8, jt8);
    __syncthreads();                                    // B3
    if (tid < 256){
      float q = 0.f;
#pragma unroll
      for (int g = 0; g < 16; ++g) q += s_part[g*256 + tid];
      s_q[tid] = q;
    } else if (tid < 512){
      int j = tid - 256;
      float d = 0.f;
#pragma unroll
      for (int g = 0; g < 16; ++g) d += s_part[4096 + g*256 + j];
      s_dq[j] = d;
    }
    __syncthreads();                                    // B4

    // ==== P3: scores + softmax (no max-subtract; |e| <= ||v||_1 ~ 10) ====
    {
      float a0=0,a1=0,a2=0,a3=0;
#pragma unroll 4
      for (int hh = 0; hh < 16; ++hh){
        int h = kg8*16 + hh;
        uint2 pv = pm2[(size_t)h*64 + jt8];
        float qh = s_q[h], vh = s_v[h];
        a0 = fmaf(vh, tanh_(b2f_lo(pv.x)+qh), a0);
        a1 = fmaf(vh, tanh_(b2f_hi(pv.x)+qh), a1);
        a2 = fmaf(vh, tanh_(b2f_lo(pv.y)+qh), a2);
        a3 = fmaf(vh, tanh_(b2f_hi(pv.y)+qh), a3);
      }
      *(float4*)(s_part + kg8*256 + jt8*4) = make_float4(a0,a1,a2,a3);
    }
    __syncthreads();                                    // B5
    float ex = 0.f;
    if (tid < TE_){
      float e = 0.f;
#pragma unroll
      for (int g = 0; g < 16; ++g) e += s_part[g*256 + tid];
      ex = __expf(e);
      float s = ex;
      for (int o = 32; o; o >>= 1) s += __shfl_down(s, o, 64);
      if ((tid & 63) == 0) s_red[tid >> 6] = s;
    }
    __syncthreads();                                    // B6
    if (tid < TE_){
      float s = (s_red[0]+s_red[1])+(s_red[2]+s_red[3]);
      float al = ex / s;
      s_al[tid] = al;
      aln_b[(size_t)t*TE_ + tid] = al;
    }
    __syncthreads();                                    // B7

    // ==== P4: context av = sum_te al[te]*enc[te,:] (enc bf16 [te][h]) ====
    {
      float a0=0,a1=0,a2=0,a3=0;
#pragma unroll 4
      for (int tt = 0; tt < 16; ++tt){
        int te = kg8*16 + tt;
        float alv = s_al[te];
        uint2 ev = en2[(size_t)te*64 + jt8];
        a0 = fmaf(alv, b2f_lo(ev.x), a0);
        a1 = fmaf(alv, b2f_hi(ev.x), a1);
        a2 = fmaf(alv, b2f_lo(ev.y), a2);
        a3 = fmaf(alv, b2f_hi(ev.y), a3);
      }
      *(float4*)(s_part + kg8*256 + jt8*4) = make_float4(a0,a1,a2,a3);
    }
    __syncthreads();                                    // B8
    if (tid < H_){
      float av = 0.f;
#pragma unroll
      for (int g = 0; g < 16; ++g) av += s_part[g*256 + tid];
      s_av[tid] = av;
    }
    __syncthreads();                                    // B9

    // ==== P5: wpB@av, dec = wpA@ah + wpB@av + bp ====
    mv256_single(wpB2, s_av, s_part + kg8*256, kg8, jt8);
    __syncthreads();                                    // B10
    if (tid < H_){
      float d = s_dq[tid] + r_bp;
#pragma unroll
      for (int g = 0; g < 16; ++g) d += s_part[g*256 + tid];
      s_dec[tid] = d;
    }
    __syncthreads();                                    // B11

    // ==== P6: decoder GRU1 ====
    if (tid < 768){
      const int kg = tid / 192, jt = tid - (tid/192)*192;
      mv768_single(g1wih2, s_dec, s_part + kg*768, kg, jt);
    }
    __syncthreads();                                    // B12
    if (tid < H_){
      float gi0 = s_part[tid]     + s_part[768+tid]  + s_part[1536+tid] + s_part[2304+tid] + r_1bi0;
      float gi1 = s_part[256+tid] + s_part[1024+tid] + s_part[1792+tid] + s_part[2560+tid] + r_1bi1;
      float gi2 = s_part[512+tid] + s_part[1280+tid] + s_part[2048+tid] + s_part[2816+tid] + r_1bi2;
      float h1n = gru_gate(gi0,gi1,gi2, s_g1h[tid], s_g1h[256+tid], s_g1h[512+tid], s_h1[tid]);
      s_h1[tid] = h1n;
      s_dec[tid] += h1n;
    }
    __syncthreads();                                    // B13

    // ==== P7: decoder GRU2 + store ====
    if (tid < 768){
      const int kg = tid / 192, jt = tid - (tid/192)*192;
      mv768_single(g2wih2, s_dec, s_part + kg*768, kg, jt);
    }
    __syncthreads();                                    // B14
    if (tid < H_){
      float gi0 = s_part[tid]     + s_part[768+tid]  + s_part[1536+tid] + s_part[2304+tid] + r_2bi0;
      float gi1 = s_part[256+tid] + s_part[1024+tid] + s_part[1792+tid] + s_part[2560+tid] + r_2bi1;
      float gi2 = s_part[512+tid] + s_part[1280+tid] + s_part[2048+tid] + s_part[2816+tid] + r_2bi2;
      float h2n = gru_gate(gi0,gi1,gi2, s_g2h[tid], s_g2h[256+tid], s_g2h[512+tid], s_h2[tid]);
      s_h2[tid] = h2n;
      float d = s_dec[tid] + h2n;
      s_dec[tid] = d;
      dec_b[(size_t)t*H_ + tid] = d;
    }
    __syncthreads();                                    // B15
  }
}

// ---------------- host ----------------
extern "C" void kernel_launch(void* const* d_in, const int* in_sizes, int n_in,
                              void* d_out, int out_size, void* d_ws, size_t ws_size,
                              hipStream_t stream)
{
  const float* enc   = (const float*)d_in[0];
  const float* tgt   = (const float*)d_in[1];
  const float* pw1   = (const float*)d_in[2];
  const float* pb1   = (const float*)d_in[3];
  const float* pw2   = (const float*)d_in[4];
  const float* pb2   = (const float*)d_in[5];
  const float* awih  = (const float*)d_in[6];
  const float* awhh  = (const float*)d_in[7];
  const float* abih  = (const float*)d_in[8];
  const float* abhh  = (const float*)d_in[9];
  const float* wq    = (const float*)d_in[10];
  const float* wm    = (const float*)d_in[11];
  const float* vat   = (const float*)d_in[12];
  const float* wp    = (const float*)d_in[13];
  const float* bp    = (const float*)d_in[14];
  const float* g1wih = (const float*)d_in[15];
  const float* g1whh = (const float*)d_in[16];
  const float* g1bih = (const float*)d_in[17];
  const float* g1bhh = (const float*)d_in[18];
  const float* g2wih = (const float*)d_in[19];
  const float* g2whh = (const float*)d_in[20];
  const float* g2bih = (const float*)d_in[21];
  const float* g2bhh = (const float*)d_in[22];
  const float* wo    = (const float*)d_in[23];
  const float* bo    = (const float*)d_in[24];

  float* ws = (float*)d_ws;
  size_t off = 0;
  auto alloc = [&](size_t n){ float* p = ws + off; off += (n + 3) & ~(size_t)3; return p; };

  // fp32 transposed weights (prologue/epilogue GEMMs)
  float* wmT    = alloc(65536);
  float* w1T    = alloc(102400);
  float* w2T    = alloc(32768);
  float* awihPT = alloc(98304);
  float* woT    = alloc(102400);
  // bf16 transposed weights (alloc in float units = ushort_count/2)
  unsigned short* awihA16 = (unsigned short*)alloc(98304);
  unsigned short* awhh16  = (unsigned short*)alloc(98304);
  unsigned short* wq16    = (unsigned short*)alloc(32768);
  unsigned short* wp16    = (unsigned short*)alloc(65536);
  unsigned short* g1wih16 = (unsigned short*)alloc(98304);
  unsigned short* g1whh16 = (unsigned short*)alloc(98304);
  unsigned short* g2wih16 = (unsigned short*)alloc(98304);
  unsigned short* g2whh16 = (unsigned short*)alloc(98304);
  // bf16 activations
  unsigned short* pm16  = (unsigned short*)alloc(4194304);   // [B][H][TE] bf16
  unsigned short* enc16 = (unsigned short*)alloc(4194304);   // [B][TE][H] bf16
  // fp32 activation buffers
  float* decb   = alloc((size_t)BT_*H_);        // also prenet1 output (aliased lifetimes)
  float* p2f    = alloc((size_t)BT_*PRE_);
  float* preGIf = alloc((size_t)BT_*3*H_);
  float* p1f = decb;

  // ---- 1. transposes / casts ----
  TDs td;
  const float* srcs[14] = { wm,  pw1, pw2, awih, wo,  awih, awhh, wq,  wp,  g1wih, g1whh, g2wih, g2whh, enc };
  void* dsts[14] = { wmT, w1T, w2T, awihPT, woT, awihA16, awhh16, wq16, wp16, g1wih16, g1whh16, g2wih16, g2whh16, enc16 };
  int   Ns[14]   = { 256, 256, 128, 768,  400, 768, 768, 256, 256, 768, 768, 768, 768, B_*TE_*H_ };
  int   Kss[14]  = { 256, 400, 256, 384,  256, 384, 256, 256, 512, 256, 256, 256, 256, 1 };
  int   c0s[14]  = { 0,   0,   0,   0,    0,   128, 0,   0,   0,   0,   0,   0,   0,   0 };
  int   Kes[14]  = { 256, 400, 256, 128,  256, 256, 256, 256, 512, 256, 256, 256, 256, 1 };
  int   bfs[14]  = { 0,   0,   0,   0,    0,   1,   1,   1,   1,   1,   1,   1,   1,   1 };
  int blk = 0;
  for (int i = 0; i < 14; ++i){
    td.d[i] = { srcs[i], dsts[i], Ns[i], Kss[i], c0s[i], Kes[i], bfs[i], blk };
    long nk = (long)Ns[i]*Kes[i];
    blk += (int)((nk + 255) / 256);
  }
  transpose_cast<<<blk, 256, 0, stream>>>(td);

  // ---- 2. prenet + preGI (teacher-forced, loop-invariant) ----
  gemm_k<1, true, 0><<<dim3(BT_/64, 4), 256, 0, stream>>>(tgt, 0,   w1T,    256, 400, pb1,  p1f);
  gemm_k<0, true, 0><<<dim3(BT_/64, 2), 256, 0, stream>>>(p1f, 256, w2T,    128, 256, pb2,  p2f);
  gemm_k<0, false,0><<<dim3(BT_/64,12), 256, 0, stream>>>(p2f, 128, awihPT, 768, 128, abih, preGIf);
  // ---- 3. pm = enc @ wm.T, stored bf16 [b][h][te] ----
  gemm_k<0, false,2><<<dim3((B_*TE_)/64, 4), 256, 0, stream>>>(enc, 256, wmT, 256, 256, nullptr, (float*)pm16);

  // ---- 4. recurrence ----
  DP P;
  P.preGI = preGIf; P.pm16 = pm16; P.enc16 = enc16;
  P.awihA = awihA16; P.awhh = awhh16; P.wq = wq16; P.wp = wp16;
  P.g1wih = g1wih16; P.g1whh = g1whh16; P.g2wih = g2wih16; P.g2whh = g2whh16;
  P.abhh = abhh; P.g1bih = g1bih; P.g1bhh = g1bhh; P.g2bih = g2bih; P.g2bhh = g2bhh;
  P.bp = bp; P.v_attn = vat;
  P.decbuf = decb;
  P.aln = (float*)d_out + (size_t)BT_*OUT_;
  decoder_kernel<<<B_, 1024, 0, stream>>>(P);

  // ---- 5. deferred output projection ----
  gemm_k<0, false,0><<<dim3(BT_/64, 7), 256, 0, stream>>>(decb, 256, woT, 400, 256, bo, (float*)d_out);
}